// Round 6
// baseline (464.696 us; speedup 1.0000x reference)
//
#include <hip/hip_runtime.h>
#include <hip/hip_bf16.h>
#include <stdint.h>

// GroupedQAttention on MI355X.
// cast x->bf16, transpose-cast weights -> bf16 BT,
// GEMM1 (256^2 4-phase, A 3-buf / B 2-buf, balanced m201-style phases) -> qkvw,
// fused tiny-attention*w -> ow (bf16), GEMM2 (same) -> fp32 out.
// R3: row-major XCD chunking + plain stores (col-major / NT stores regressed).
// R5: supertile cut FETCH 307->204MB (kept); A-prefetch depth was NOT the
//     bottleneck. R6: balance reads {4,8,8,4} & stages {2,2,2,2} per phase,
//     split a0/a1 regs so A0-next read moves to ph2, single vmcnt(4)/tile.

typedef __bf16 bf16;
typedef __bf16 bf16x8 __attribute__((ext_vector_type(8)));
typedef float f32x4 __attribute__((ext_vector_type(4)));

__device__ __forceinline__ void gload16(const bf16* g, bf16* l) {
  __builtin_amdgcn_global_load_lds(
      (const __attribute__((address_space(1))) void*)g,
      (__attribute__((address_space(3))) void*)l, 16, 0, 0);
}

#define BAR() asm volatile("s_barrier" ::: "memory")
#define SB() __builtin_amdgcn_sched_barrier(0)
#define LGKM0 asm volatile("s_waitcnt lgkmcnt(0)" ::: "memory")
#define PRIO1 __builtin_amdgcn_s_setprio(1)
#define PRIO0 __builtin_amdgcn_s_setprio(0)

// ---------- 256x256-tile GEMM: C[M][N] = A[M][1024] * BT[N][1024]^T ----------
// 512 threads = 8 waves (2Mx4N). BK=64, 16 K-tiles.
// LDS 160KiB: A buffers 3x32KB at 0/32K/64K (tile T reads buf T%3),
//             B buffers 2x32KB at 96K/128K (tile T reads buf T%2).
// Swizzle involution on [128][64]bf16 halves: byte ^= ((byte>>7)&7)<<4.
// Per tile (reads balanced {4,8,8,4}, stages 2 gloads/phase, 1 vmcnt):
//  ph0: stageA-h0(T+2) | BAR lgkm0 | readB1 | MFMA(0,0)[a0,b01]
//  ph1: stageA-h1(T+2) | BAR lgkm0 | MFMA(0,1)[a0,b23] | readA1->a1
//  ph2: BAR vmcnt(4) lgkm0 | stageB-h0(T+2) | MFMA(1,1)[a1,b23] | readA0N->a0
//  ph3: stageB-h1(T+2) | BAR | MFMA(1,0)[a1,b01] | readB0N
// Ledger: A(T-1)-buf reads (A0N@ph2(T-2), A1@ph1(T-1)) drained by own-wave
//   lgkm0 @ph0(T-1)/ph2(T-1), cross-wave by ph3(T-1) BAR < stages @ph0/1(T).
//   B(T)-buf reads (B0N@ph3(T-1), B1@ph0(T)) drained @ph0/ph1(T) lgkm0,
//   cross-wave by ph2(T) BAR < stageB @ph2/3(T). RAW: vmcnt(4)@ph2(T) leaves
//   exactly A(T+2)x4 newest in flight => A(T+1) (read @ph2(T)) and B(T+1)
//   (read @ph3(T)) landed. ph3 needs no lgkm wait: MFMA(1,0) operands were
//   drained @ph2/ph0; only A0N (8 reads, consumed next ph0) outstanding.
#define READ_AX(dst, mq, AO)                                                  \
  {                                                                           \
    _Pragma("unroll") for (int i = 0; i < 4; ++i)                             \
        _Pragma("unroll") for (int kk = 0; kk < 2; ++kk)                      \
            dst[i][kk] = *(const bf16x8*)(lds + (AO) +                        \
                                          ((mq)*64 + i * 16 + fr) * 128 +     \
                                          ((kk * 64 + fkb) ^ xo));            \
  }
#define READ_B(nh, BO)                                                        \
  {                                                                           \
    _Pragma("unroll") for (int j = 0; j < 2; ++j)                             \
        _Pragma("unroll") for (int kk = 0; kk < 2; ++kk)                      \
            b[(nh)*2 + j][kk] = *(const bf16x8*)(lds + (BO) +                 \
                                                 (bro + (nh)*32 + j * 16 + fr) * 128 + \
                                                 ((kk * 64 + fkb) ^ xo));     \
  }
#define MFMA_Q(arr, mq, nh)                                                   \
  {                                                                           \
    _Pragma("unroll") for (int i = 0; i < 4; ++i)                             \
        _Pragma("unroll") for (int j = 0; j < 2; ++j) {                       \
      acc[(mq)*4 + i][(nh)*2 + j] = __builtin_amdgcn_mfma_f32_16x16x32_bf16(  \
          arr[i][0], b[(nh)*2 + j][0], acc[(mq)*4 + i][(nh)*2 + j], 0, 0, 0); \
      acc[(mq)*4 + i][(nh)*2 + j] = __builtin_amdgcn_mfma_f32_16x16x32_bf16(  \
          arr[i][1], b[(nh)*2 + j][1], acc[(mq)*4 + i][(nh)*2 + j], 0, 0, 0); \
    }                                                                         \
  }
#define STAGE_AH(h, X, base)                                                  \
  {                                                                           \
    const bf16* g = gA + ((h)*128) * 1024 + (X)*64;                           \
    gload16(g, (bf16*)(lds + (base) + (h)*16384 + wv * 1024));                \
    gload16(g + 64 * 1024, (bf16*)(lds + (base) + (h)*16384 + 8192 + wv * 1024)); \
  }
#define STAGE_BH(h, X)                                                        \
  {                                                                           \
    const int ro = 98304 + ((X)&1) * 32768 + (h)*16384;                       \
    const bf16* g = gB + ((h)*128) * 1024 + (X)*64;                           \
    gload16(g, (bf16*)(lds + ro + wv * 1024));                                \
    gload16(g + 64 * 1024, (bf16*)(lds + ro + 8192 + wv * 1024));             \
  }

template <typename OutT>
__global__ __launch_bounds__(512, 2)
void gemm256(const bf16* __restrict__ A, const bf16* __restrict__ BT,
             OutT* __restrict__ C, int N, int super) {
  constexpr int K = 1024;
  __shared__ __align__(16) char smem[163840];
  char* lds = smem;

  const int tid = threadIdx.x;
  const int lane = tid & 63;
  const int wv = tid >> 6;
  const int wr = wv >> 2;  // 0..1
  const int wc = wv & 3;   // 0..3

  // XCD chunking: per-XCD contiguous range; within it, 8x4 supertiles so the
  // ~32 concurrent blocks/XCD share A row-panels (x4) and B col-panels (x8).
  const int gx = gridDim.x;
  const int nwg = gx * gridDim.y;
  const int bid = blockIdx.y * gx + blockIdx.x;
  const int xcd = bid & 7;
  const int l = bid >> 3;
  long trow, tcol;
  if (super) {  // requires (nwg/8)/gx == 16 and gx%4==0
    const int s = l >> 5, i = l & 31;
    const int colS = gx >> 2;
    trow = xcd * 16 + (s / colS) * 8 + (i >> 2);
    tcol = (s % colS) * 4 + (i & 3);
  } else {
    const int swz = xcd * (nwg >> 3) + l;
    trow = swz / gx;
    tcol = swz % gx;
  }
  const long row0 = trow * 256;
  const long col0 = tcol * 256;

  // staging source (pre-swizzled so linear global_load_lds dest == swizzled layout)
  const int srow = tid >> 3;  // 0..63
  const int scol = (((tid & 7) * 16) ^ ((srow & 7) << 4)) >> 1;  // elements
  const bf16* gA = A + (row0 + srow) * K + scol;
  const bf16* gB = BT + (col0 + srow) * K + scol;

  // fragment read addressing
  const int fr = lane & 15;
  const int fkb = (lane >> 4) * 16;  // byte offset of k-slice
  const int xo = (fr & 7) << 4;
  const int bro = (wc & 1) * 64;

  bf16x8 a0[4][2], a1[4][2], b[4][2];
  f32x4 acc[8][4] = {};

  // prologue: interleave A(0),B(0),A(1),B(1); vmcnt(8) drains A(0),B(0)
  STAGE_AH(0, 0, 0); STAGE_AH(1, 0, 0);
  STAGE_BH(0, 0); STAGE_BH(1, 0);
  STAGE_AH(0, 1, 32768); STAGE_AH(1, 1, 32768);
  STAGE_BH(0, 1); STAGE_BH(1, 1);
  asm volatile("s_waitcnt vmcnt(8)" ::: "memory");
  SB(); BAR(); SB();
  READ_AX(a0, 0, wr * 16384);
  READ_B(0, 98304 + (wc >> 1) * 16384);
  SB();

  int ac0 = 0, ac1 = 32768, ac2 = 65536;  // A bufs: cur, next, stage-target
  for (int T = 0; T < 16; ++T) {
    const int aoff = ac0 + wr * 16384;
    const int aoffN = ac1 + wr * 16384;
    const int boff = 98304 + (T & 1) * 32768 + (wc >> 1) * 16384;
    const int boffN = 98304 + ((T + 1) & 1) * 32768 + (wc >> 1) * 16384;
    // ph0
    if (T < 14) STAGE_AH(0, T + 2, ac2);
    SB(); BAR(); LGKM0; SB();
    READ_B(1, boff); SB();
    PRIO1; MFMA_Q(a0, 0, 0); PRIO0; SB();
    // ph1
    if (T < 14) STAGE_AH(1, T + 2, ac2);
    SB(); BAR(); LGKM0; SB();
    PRIO1; MFMA_Q(a0, 0, 1); PRIO0; SB();
    READ_AX(a1, 1, aoff); SB();
    // ph2
    BAR();
    if (T < 14) {
      asm volatile("s_waitcnt vmcnt(4)" ::: "memory");
    } else if (T == 14) {
      asm volatile("s_waitcnt vmcnt(0)" ::: "memory");
    }
    LGKM0; SB();
    if (T < 14) STAGE_BH(0, T + 2);
    SB();
    PRIO1; MFMA_Q(a1, 1, 1); PRIO0; SB();
    if (T < 15) READ_AX(a0, 0, aoffN);
    SB();
    // ph3
    if (T < 14) STAGE_BH(1, T + 2);
    SB(); BAR(); SB();
    PRIO1; MFMA_Q(a1, 1, 0); PRIO0; SB();
    if (T < 15) READ_B(0, boffN);
    SB();
    const int t = ac0; ac0 = ac1; ac1 = ac2; ac2 = t;
  }

  // epilogue: C/D layout col=lane&15, row=(lane>>4)*4+reg
  const int crow = (lane >> 4) * 4;
  const int ccol = lane & 15;
  const long rb = row0 + wr * 128;
  const long cb = col0 + wc * 64;
#pragma unroll
  for (int m = 0; m < 8; ++m)
#pragma unroll
    for (int n = 0; n < 4; ++n)
#pragma unroll
      for (int i = 0; i < 4; ++i)
        C[(rb + m * 16 + crow + i) * (long)N + cb + n * 16 + ccol] =
            (OutT)acc[m][n][i];
}

// ---------------- fused tiny attention ----------------
__device__ __forceinline__ void load16f(const bf16* p, float* f) {
  const uint4* u = (const uint4*)p;
  uint4 a = u[0], b = u[1];
  uint32_t w[8] = {a.x, a.y, a.z, a.w, b.x, b.y, b.z, b.w};
#pragma unroll
  for (int j = 0; j < 8; ++j) {
    f[2 * j] = __uint_as_float(w[j] << 16);
    f[2 * j + 1] = __uint_as_float(w[j] & 0xffff0000u);
  }
}

// block = (s_hi, g, bz); 256 threads = 16 s_lo x 16 h1
__global__ __launch_bounds__(256)
void attn_fuse(const bf16* __restrict__ qkvw, bf16* __restrict__ ow,
               int b0, long bstride) {
  __shared__ bf16 data[16 * 1024];
  const int s_hi = blockIdx.x;
  const int g = blockIdx.y;
  const int bz = blockIdx.z;
  const int b = b0 + bz;
  const bf16* base = qkvw + (long)bz * bstride;
  const int tid = threadIdx.x;

#pragma unroll
  for (int i = 0; i < 8; ++i) {
    int c = tid + i * 256;
    int h = c >> 7;
    int col = (c & 127) * 8;
    *(uint4*)&data[h * 1024 + col] =
        *(const uint4*)(base + (long)(h * 256 + s_hi) * 4096 + g * 1024 + col);
  }
  __syncthreads();

  const int s_lo = tid >> 4;
  const int h1 = tid & 15;
  const int off = s_lo * 16;

  float q[16], p[16], o[16];
  load16f(&data[h1 * 1024 + off], q);

  float mx = -1e30f;
#pragma unroll
  for (int h2 = 0; h2 < 16; ++h2) {
    float kf[16];
    load16f(&data[h2 * 1024 + 256 + off], kf);
    float s = 0.f;
#pragma unroll
    for (int d = 0; d < 16; ++d) s += q[d] * kf[d];
    s *= 0.25f;  // HD^-0.5, HD=16
    p[h2] = s;
    mx = fmaxf(mx, s);
  }
  float sum = 0.f;
#pragma unroll
  for (int h2 = 0; h2 < 16; ++h2) {
    float e = __expf(p[h2] - mx);
    p[h2] = e;
    sum += e;
  }
  const float inv = 1.f / sum;
#pragma unroll
  for (int d = 0; d < 16; ++d) o[d] = 0.f;
#pragma unroll
  for (int h2 = 0; h2 < 16; ++h2) {
    float vf[16];
    load16f(&data[h2 * 1024 + 512 + off], vf);
    const float av = p[h2] * inv;
#pragma unroll
    for (int d = 0; d < 16; ++d) o[d] += av * vf[d];
  }
  float wf[16];
  load16f(&data[h1 * 1024 + 768 + off], wf);

  const int bp = g * 8 + b;  // concat index along axis 0
  const long R = (long)(bp >> 2) * 4096 + (bp & 3) * 1024 + h1 * 64 + (s_hi >> 2);
  const int cbo = (s_hi & 3) * 256 + off;
  union { uint4 u[2]; bf16 hh[16]; } st;
#pragma unroll
  for (int d = 0; d < 16; ++d) st.hh[d] = (bf16)(o[d] * wf[d]);
  uint4* dst = (uint4*)&ow[R * 1024 + cbo];
  dst[0] = st.u[0];
  dst[1] = st.u[1];
}

// ---------------- casts ----------------
__global__ __launch_bounds__(256)
void cast_x_kernel(const float* __restrict__ in, bf16* __restrict__ out, long n4) {
  long i = (long)blockIdx.x * 256 + threadIdx.x;
  if (i >= n4) return;
  float4 v = ((const float4*)in)[i];
  union { uint2 d; bf16 h[4]; } r;
  r.h[0] = (bf16)v.x; r.h[1] = (bf16)v.y; r.h[2] = (bf16)v.z; r.h[3] = (bf16)v.w;
  ((uint2*)out)[i] = r.d;
}

// out[C][R] = bf16(in[R][C])  (transpose-cast, 64x64 tiles)
__global__ __launch_bounds__(256)
void tcast_kernel(const float* __restrict__ in, bf16* __restrict__ out, int R, int C) {
  __shared__ float t[64][65];
  const int c0 = blockIdx.x * 64, r0 = blockIdx.y * 64;
  const int lr = threadIdx.x >> 6;
  const int lc = threadIdx.x & 63;
#pragma unroll
  for (int i = 0; i < 16; ++i)
    t[lr + i * 4][lc] = in[(long)(r0 + lr + i * 4) * C + c0 + lc];
  __syncthreads();
#pragma unroll
  for (int i = 0; i < 16; ++i) {
    int oc = lr + i * 4;
    out[(long)(c0 + oc) * R + r0 + lc] = (bf16)t[lc][oc];
  }
}

// ---------------- launch ----------------
extern "C" void kernel_launch(void* const* d_in, const int* in_sizes, int n_in,
                              void* d_out, int out_size, void* d_ws, size_t ws_size,
                              hipStream_t stream) {
  const float* x = (const float*)d_in[0];
  const float* w_qkvw = (const float*)d_in[1];
  const float* w_out = (const float*)d_in[2];
  float* out = (float*)d_out;

  char* ws = (char*)d_ws;
  size_t off = 0;
  bf16* x_bf = (bf16*)(ws + off); off += (size_t)32768 * 1024 * 2;
  bf16* bt1  = (bf16*)(ws + off); off += (size_t)4096 * 1024 * 2;
  bf16* bt2  = (bf16*)(ws + off); off += (size_t)1024 * 1024 * 2;
  bf16* owb  = (bf16*)(ws + off); off += (size_t)32768 * 1024 * 2;
  bf16* qk   = (bf16*)(ws + off);
  const size_t rem = ws_size > off ? ws_size - off : 0;
  const size_t full_need = (size_t)32768 * 4096 * 2;

  cast_x_kernel<<<32768, 256, 0, stream>>>(x, x_bf, (long)8388608);
  tcast_kernel<<<dim3(64, 16), 256, 0, stream>>>(w_qkvw, bt1, 1024, 4096);
  tcast_kernel<<<dim3(16, 16), 256, 0, stream>>>(w_out, bt2, 1024, 1024);

  if (rem >= full_need) {
    gemm256<bf16><<<dim3(16, 128), 512, 0, stream>>>(x_bf, bt1, qk, 4096, 1);
    attn_fuse<<<dim3(256, 4, 8), 256, 0, stream>>>(qk, owb, 0, (long)4096 * 4096);
  } else {
    for (int b = 0; b < 8; ++b) {
      gemm256<bf16><<<dim3(16, 16), 512, 0, stream>>>(
          x_bf + (size_t)b * 4096 * 1024, bt1, qk, 4096, 0);
      attn_fuse<<<dim3(256, 4, 1), 256, 0, stream>>>(qk, owb, b, 0);
    }
  }
  gemm256<float><<<dim3(4, 128), 512, 0, stream>>>(owb, bt2, out, 1024, 1);
}

// Round 8
// 462.679 us; speedup vs baseline: 1.0044x; 1.0044x over previous
//
#include <hip/hip_runtime.h>
#include <hip/hip_bf16.h>
#include <stdint.h>

// GroupedQAttention on MI355X.
// cast x->bf16, transpose-cast weights -> bf16 BT,
// GEMM1 (256^2 8-phase/2-tile, constant LDS offsets) -> qkvw,
// fused tiny-attention*w -> ow (bf16), GEMM2 (same) -> fp32 out.
// R3: row-major XCD chunking + plain stores. R5: supertile (kept).
// R7 FAILED: vmcnt is PER-WAVE; a read of a staged region must follow
// {VM-gate ; s_barrier} to see OTHER waves' global_load_lds. R8: gates at
// ph4/ph8 immediately before the phase's first BAR; all dependent reads in
// the phases AFTER that barrier. Full RAW/WAR ledger in comments below.

typedef __bf16 bf16;
typedef __bf16 bf16x8 __attribute__((ext_vector_type(8)));
typedef float f32x4 __attribute__((ext_vector_type(4)));

__device__ __forceinline__ void gload16(const bf16* g, bf16* l) {
  __builtin_amdgcn_global_load_lds(
      (const __attribute__((address_space(1))) void*)g,
      (__attribute__((address_space(3))) void*)l, 16, 0, 0);
}

#define BAR() asm volatile("s_barrier" ::: "memory")
#define SB() __builtin_amdgcn_sched_barrier(0)
#define LGKM0 asm volatile("s_waitcnt lgkmcnt(0)" ::: "memory")
#define VM4 asm volatile("s_waitcnt vmcnt(4)" ::: "memory")
#define VM0 asm volatile("s_waitcnt vmcnt(0)" ::: "memory")
#define PRIO1 __builtin_amdgcn_s_setprio(1)
#define PRIO0 __builtin_amdgcn_s_setprio(0)

// ---------- 256x256-tile GEMM: C[M][N] = A[M][1024] * BT[N][1024]^T ----------
// 512 threads = 8 waves (2Mx4N). BK=64; 16 K-tiles = 8 pairs (E=2j, O=2j+1).
// LDS 128KiB, constant offsets:
//   A0lo 0      A0hi 16384   A1lo 32768  A1hi 49152    (A0=E tiles, A1=O)
//   B0lo 65536  B0hi 81920   B1lo 98304  B1hi 114688   (B0=E, B1=O)
// Swizzle involution on [128][64]bf16 halves: byte ^= ((byte>>7)&7)<<4.
// Phase = [reads][stage][gate?][BAR][lgkm0][16 MFMA][BAR].
//  ph1: rd a0<-A0mq0, b01<-B0nh0 | st B(O)lo | MFMA(0,0)
//  ph2: rd a1<-A0mq1             | st B(O)hi | MFMA(1,0)
//  ph3: rd b23<-B0nh1            | st A(E+2)lo | MFMA(1,1)
//  ph4:                          | st A(E+2)hi, VM4 | MFMA(0,1)
//  ph5: rd a0<-A1mq0, b01<-B1nh0 | st B(E+2)lo | MFMA(0,0)
//  ph6: rd a1<-A1mq1             | st B(E+2)hi | MFMA(1,0)
//  ph7: rd b23<-B1nh1            | st A(O+2)lo | MFMA(1,1)
//  ph8:                          | st A(O+2)hi, VM4 | MFMA(0,1)
// RAW: ph4 VM4 (before ph4 BAR) leaves A(E+2)x4 newest; drains A(O)x4
//  (staged ph7/8 prev) + B(O)x4 (ph1/2) => ph5/6/7 reads of A1,B1 are after
//  {VM4;BAR}: globally landed. ph8 VM4 leaves A(O+2)x4; drains A(E+2)+B(E+2)
//  => ph1/2/3 reads of A0,B0 safe. Prologue {VM4;BAR} covers pair-0 ph1-3.
// WAR: every stage follows the victim region's last-read phase's
//  LGKM0 + trailing BAR (B1@ph1<-last rd ph7 prev; A0@ph3<-ph2; B0@ph5<-ph3;
//  A1@ph7<-ph6). Last pair: ph4 uses VM0 (drain all), ph8 no gate/stage.
#define READ_A8(dst, base, mq)                                                \
  {                                                                           \
    _Pragma("unroll") for (int i = 0; i < 4; ++i)                             \
        _Pragma("unroll") for (int kk = 0; kk < 2; ++kk)                      \
            dst[i][kk] = *(const bf16x8*)(lds + (base) + ahalf +              \
                                          ((mq)*64 + i * 16 + fr) * 128 +     \
                                          ((kk * 64 + fkb) ^ xo));            \
  }
#define READ_B4(base, nh)                                                     \
  {                                                                           \
    _Pragma("unroll") for (int j2 = 0; j2 < 2; ++j2)                          \
        _Pragma("unroll") for (int kk = 0; kk < 2; ++kk)                      \
            b[(nh)*2 + j2][kk] = *(const bf16x8*)(lds + (base) + bhalf +      \
                                                  (bro + (nh)*32 + j2 * 16 + fr) * 128 + \
                                                  ((kk * 64 + fkb) ^ xo));    \
  }
#define MFMA_Q(arr, mq, nh)                                                   \
  {                                                                           \
    _Pragma("unroll") for (int i = 0; i < 4; ++i)                             \
        _Pragma("unroll") for (int j2 = 0; j2 < 2; ++j2) {                    \
      acc[(mq)*4 + i][(nh)*2 + j2] = __builtin_amdgcn_mfma_f32_16x16x32_bf16( \
          arr[i][0], b[(nh)*2 + j2][0], acc[(mq)*4 + i][(nh)*2 + j2], 0, 0, 0); \
      acc[(mq)*4 + i][(nh)*2 + j2] = __builtin_amdgcn_mfma_f32_16x16x32_bf16( \
          arr[i][1], b[(nh)*2 + j2][1], acc[(mq)*4 + i][(nh)*2 + j2], 0, 0, 0); \
    }                                                                         \
  }
#define STAGE(gsrc, lbase)                                                    \
  {                                                                           \
    gload16((gsrc), (bf16*)(lds + (lbase) + wv * 1024));                      \
    gload16((gsrc) + 64 * 1024, (bf16*)(lds + (lbase) + 8192 + wv * 1024));   \
  }

template <typename OutT>
__global__ __launch_bounds__(512, 2)
void gemm256(const bf16* __restrict__ A, const bf16* __restrict__ BT,
             OutT* __restrict__ C, int N, int super) {
  constexpr int K = 1024;
  __shared__ __align__(16) char smem[131072];
  char* lds = smem;

  const int tid = threadIdx.x;
  const int lane = tid & 63;
  const int wv = tid >> 6;
  const int wr = wv >> 2;  // 0..1
  const int wc = wv & 3;   // 0..3

  // XCD chunking + 8x4 supertiles (R5: FETCH 307->204MB)
  const int gx = gridDim.x;
  const int nwg = gx * gridDim.y;
  const int bid = blockIdx.y * gx + blockIdx.x;
  const int xcd = bid & 7;
  const int l = bid >> 3;
  long trow, tcol;
  if (super) {  // requires (nwg/8)/gx == 16 and gx%4==0
    const int s = l >> 5, i = l & 31;
    const int colS = gx >> 2;
    trow = xcd * 16 + (s / colS) * 8 + (i >> 2);
    tcol = (s % colS) * 4 + (i & 3);
  } else {
    const int swz = xcd * (nwg >> 3) + l;
    trow = swz / gx;
    tcol = swz % gx;
  }
  const long row0 = trow * 256;
  const long col0 = tcol * 256;

  // staging source (pre-swizzled so linear global_load_lds dest == swizzled layout)
  const int srow = tid >> 3;  // 0..63
  const int scol = (((tid & 7) * 16) ^ ((srow & 7) << 4)) >> 1;  // elements
  const bf16* gA = A + (row0 + srow) * K + scol;
  const bf16* gB = BT + (col0 + srow) * K + scol;

  // fragment read addressing
  const int fr = lane & 15;
  const int fkb = (lane >> 4) * 16;  // byte offset of k-slice
  const int xo = (fr & 7) << 4;
  const int bro = (wc & 1) * 64;
  const int ahalf = wr * 16384;
  const int bhalf = (wc >> 1) * 16384;

  bf16x8 a0[4][2], a1[4][2], b[4][2];
  f32x4 acc[8][4] = {};

  // prologue: A(0)->A0, B(0)->B0, A(1)->A1 (12 loads); VM4 leaves A(1)x4,
  // drains A(0),B(0); BAR makes them globally visible for ph1-3 reads.
  STAGE(gA, 0); STAGE(gA + 131072, 16384);
  STAGE(gB, 65536); STAGE(gB + 131072, 81920);
  STAGE(gA + 64, 32768); STAGE(gA + 131072 + 64, 49152);
  VM4;
  SB(); BAR(); SB();

  const bf16* gAm = gA;
  const bf16* gBm = gB;
  for (int j = 0; j < 8; ++j) {
    const bool nl = (j < 7);
    // ph1
    READ_A8(a0, 0, 0); READ_B4(65536, 0);
    STAGE(gBm + 64, 98304);
    SB(); BAR(); LGKM0; SB();
    PRIO1; MFMA_Q(a0, 0, 0); PRIO0; SB(); BAR();
    // ph2
    READ_A8(a1, 0, 1);
    STAGE(gBm + 131072 + 64, 114688);
    SB(); BAR(); LGKM0; SB();
    PRIO1; MFMA_Q(a1, 1, 0); PRIO0; SB(); BAR();
    // ph3
    READ_B4(65536, 1);
    if (nl) STAGE(gAm + 128, 0);
    SB(); BAR(); LGKM0; SB();
    PRIO1; MFMA_Q(a1, 1, 1); PRIO0; SB(); BAR();
    // ph4: gate before BAR (covers A1,B1 for ph5-7)
    if (nl) {
      STAGE(gAm + 131072 + 128, 16384);
      VM4;
    } else {
      VM0;
    }
    SB(); BAR(); LGKM0; SB();
    PRIO1; MFMA_Q(a0, 0, 1); PRIO0; SB(); BAR();
    // ph5
    READ_A8(a0, 32768, 0); READ_B4(98304, 0);
    if (nl) STAGE(gBm + 128, 65536);
    SB(); BAR(); LGKM0; SB();
    PRIO1; MFMA_Q(a0, 0, 0); PRIO0; SB(); BAR();
    // ph6
    READ_A8(a1, 32768, 1);
    if (nl) STAGE(gBm + 131072 + 128, 81920);
    SB(); BAR(); LGKM0; SB();
    PRIO1; MFMA_Q(a1, 1, 0); PRIO0; SB(); BAR();
    // ph7
    READ_B4(98304, 1);
    if (nl) STAGE(gAm + 192, 32768);
    SB(); BAR(); LGKM0; SB();
    PRIO1; MFMA_Q(a1, 1, 1); PRIO0; SB(); BAR();
    // ph8: gate before BAR (covers A0,B0 for next pair's ph1-3)
    if (nl) {
      STAGE(gAm + 131072 + 192, 49152);
      VM4;
    }
    SB(); BAR(); LGKM0; SB();
    PRIO1; MFMA_Q(a0, 0, 1); PRIO0; SB(); BAR();
    gAm += 128;
    gBm += 128;
  }

  // epilogue: C/D layout col=lane&15, row=(lane>>4)*4+reg
  const int crow = (lane >> 4) * 4;
  const int ccol = lane & 15;
  const long rb = row0 + wr * 128;
  const long cb = col0 + wc * 64;
#pragma unroll
  for (int m = 0; m < 8; ++m)
#pragma unroll
    for (int n = 0; n < 4; ++n)
#pragma unroll
      for (int i = 0; i < 4; ++i)
        C[(rb + m * 16 + crow + i) * (long)N + cb + n * 16 + ccol] =
            (OutT)acc[m][n][i];
}

// ---------------- fused tiny attention ----------------
__device__ __forceinline__ void load16f(const bf16* p, float* f) {
  const uint4* u = (const uint4*)p;
  uint4 a = u[0], b = u[1];
  uint32_t w[8] = {a.x, a.y, a.z, a.w, b.x, b.y, b.z, b.w};
#pragma unroll
  for (int j = 0; j < 8; ++j) {
    f[2 * j] = __uint_as_float(w[j] << 16);
    f[2 * j + 1] = __uint_as_float(w[j] & 0xffff0000u);
  }
}

// block = (s_hi, g, bz); 256 threads = 16 s_lo x 16 h1
__global__ __launch_bounds__(256)
void attn_fuse(const bf16* __restrict__ qkvw, bf16* __restrict__ ow,
               int b0, long bstride) {
  __shared__ bf16 data[16 * 1024];
  const int s_hi = blockIdx.x;
  const int g = blockIdx.y;
  const int bz = blockIdx.z;
  const int b = b0 + bz;
  const bf16* base = qkvw + (long)bz * bstride;
  const int tid = threadIdx.x;

#pragma unroll
  for (int i = 0; i < 8; ++i) {
    int c = tid + i * 256;
    int h = c >> 7;
    int col = (c & 127) * 8;
    *(uint4*)&data[h * 1024 + col] =
        *(const uint4*)(base + (long)(h * 256 + s_hi) * 4096 + g * 1024 + col);
  }
  __syncthreads();

  const int s_lo = tid >> 4;
  const int h1 = tid & 15;
  const int off = s_lo * 16;

  float q[16], p[16], o[16];
  load16f(&data[h1 * 1024 + off], q);

  float mx = -1e30f;
#pragma unroll
  for (int h2 = 0; h2 < 16; ++h2) {
    float kf[16];
    load16f(&data[h2 * 1024 + 256 + off], kf);
    float s = 0.f;
#pragma unroll
    for (int d = 0; d < 16; ++d) s += q[d] * kf[d];
    s *= 0.25f;  // HD^-0.5, HD=16
    p[h2] = s;
    mx = fmaxf(mx, s);
  }
  float sum = 0.f;
#pragma unroll
  for (int h2 = 0; h2 < 16; ++h2) {
    float e = __expf(p[h2] - mx);
    p[h2] = e;
    sum += e;
  }
  const float inv = 1.f / sum;
#pragma unroll
  for (int d = 0; d < 16; ++d) o[d] = 0.f;
#pragma unroll
  for (int h2 = 0; h2 < 16; ++h2) {
    float vf[16];
    load16f(&data[h2 * 1024 + 512 + off], vf);
    const float av = p[h2] * inv;
#pragma unroll
    for (int d = 0; d < 16; ++d) o[d] += av * vf[d];
  }
  float wf[16];
  load16f(&data[h1 * 1024 + 768 + off], wf);

  const int bp = g * 8 + b;  // concat index along axis 0
  const long R = (long)(bp >> 2) * 4096 + (bp & 3) * 1024 + h1 * 64 + (s_hi >> 2);
  const int cbo = (s_hi & 3) * 256 + off;
  union { uint4 u[2]; bf16 hh[16]; } st;
#pragma unroll
  for (int d = 0; d < 16; ++d) st.hh[d] = (bf16)(o[d] * wf[d]);
  uint4* dst = (uint4*)&ow[R * 1024 + cbo];
  dst[0] = st.u[0];
  dst[1] = st.u[1];
}

// ---------------- casts ----------------
__global__ __launch_bounds__(256)
void cast_x_kernel(const float* __restrict__ in, bf16* __restrict__ out, long n4) {
  long i = (long)blockIdx.x * 256 + threadIdx.x;
  if (i >= n4) return;
  float4 v = ((const float4*)in)[i];
  union { uint2 d; bf16 h[4]; } r;
  r.h[0] = (bf16)v.x; r.h[1] = (bf16)v.y; r.h[2] = (bf16)v.z; r.h[3] = (bf16)v.w;
  ((uint2*)out)[i] = r.d;
}

// out[C][R] = bf16(in[R][C])  (transpose-cast, 64x64 tiles)
__global__ __launch_bounds__(256)
void tcast_kernel(const float* __restrict__ in, bf16* __restrict__ out, int R, int C) {
  __shared__ float t[64][65];
  const int c0 = blockIdx.x * 64, r0 = blockIdx.y * 64;
  const int lr = threadIdx.x >> 6;
  const int lc = threadIdx.x & 63;
#pragma unroll
  for (int i = 0; i < 16; ++i)
    t[lr + i * 4][lc] = in[(long)(r0 + lr + i * 4) * C + c0 + lc];
  __syncthreads();
#pragma unroll
  for (int i = 0; i < 16; ++i) {
    int oc = lr + i * 4;
    out[(long)(c0 + oc) * R + r0 + lc] = (bf16)t[lc][oc];
  }
}

// ---------------- launch ----------------
extern "C" void kernel_launch(void* const* d_in, const int* in_sizes, int n_in,
                              void* d_out, int out_size, void* d_ws, size_t ws_size,
                              hipStream_t stream) {
  const float* x = (const float*)d_in[0];
  const float* w_qkvw = (const float*)d_in[1];
  const float* w_out = (const float*)d_in[2];
  float* out = (float*)d_out;

  char* ws = (char*)d_ws;
  size_t off = 0;
  bf16* x_bf = (bf16*)(ws + off); off += (size_t)32768 * 1024 * 2;
  bf16* bt1  = (bf16*)(ws + off); off += (size_t)4096 * 1024 * 2;
  bf16* bt2  = (bf16*)(ws + off); off += (size_t)1024 * 1024 * 2;
  bf16* owb  = (bf16*)(ws + off); off += (size_t)32768 * 1024 * 2;
  bf16* qk   = (bf16*)(ws + off);
  const size_t rem = ws_size > off ? ws_size - off : 0;
  const size_t full_need = (size_t)32768 * 4096 * 2;

  cast_x_kernel<<<32768, 256, 0, stream>>>(x, x_bf, (long)8388608);
  tcast_kernel<<<dim3(64, 16), 256, 0, stream>>>(w_qkvw, bt1, 1024, 4096);
  tcast_kernel<<<dim3(16, 16), 256, 0, stream>>>(w_out, bt2, 1024, 1024);

  if (rem >= full_need) {
    gemm256<bf16><<<dim3(16, 128), 512, 0, stream>>>(x_bf, bt1, qk, 4096, 1);
    attn_fuse<<<dim3(256, 4, 8), 256, 0, stream>>>(qk, owb, 0, (long)4096 * 4096);
  } else {
    for (int b = 0; b < 8; ++b) {
      gemm256<bf16><<<dim3(16, 16), 512, 0, stream>>>(
          x_bf + (size_t)b * 4096 * 1024, bt1, qk, 4096, 0);
      attn_fuse<<<dim3(256, 4, 1), 256, 0, stream>>>(qk, owb, b, 0);
    }
  }
  gemm256<float><<<dim3(4, 128), 512, 0, stream>>>(owb, bt2, out, 1024, 1);
}